// Round 5
// baseline (390.127 us; speedup 1.0000x reference)
//
#include <hip/hip_runtime.h>
#include <math.h>

#define BB 8
#define NN 4096
#define DIMc 256
#define HH 8
#define DH 64
#define INNERc 512

typedef unsigned short us;
typedef short s16x8 __attribute__((ext_vector_type(8)));   // 8 bf16 operand (4 VGPRs)
typedef float f32x4 __attribute__((ext_vector_type(4)));   // 16x16 C/D frag

static __device__ __forceinline__ us f2bf(float f) {
    union { float f; unsigned int u; } c; c.f = f;
    unsigned int u = c.u;
    return (us)((u + 0x7fffu + ((u >> 16) & 1u)) >> 16);   // RNE
}

#define MFMA16(a, b, c) __builtin_amdgcn_mfma_f32_16x16x32_bf16((a), (b), (c), 0, 0, 0)

// ---------------------------------------------------------------
// cast kernels
// ---------------------------------------------------------------
__global__ __launch_bounds__(256) void cast_bf16(const float* __restrict__ in,
                                                 us* __restrict__ out, int n4) {
    int idx = blockIdx.x * 256 + threadIdx.x;
    if (idx >= n4) return;
    float4 v = ((const float4*)in)[idx];
    union { us s[4]; uint2 u; } pk;
    pk.s[0] = f2bf(v.x); pk.s[1] = f2bf(v.y); pk.s[2] = f2bf(v.z); pk.s[3] = f2bf(v.w);
    ((uint2*)out)[idx] = pk.u;
}

// out[r][c] = in[c][r]; out is R x C, in row-length = R
__global__ __launch_bounds__(256) void cast_T(const float* __restrict__ in,
                                              us* __restrict__ out, int R, int C) {
    int idx = blockIdx.x * 256 + threadIdx.x;
    if (idx >= R * C) return;
    int r = idx / C, c = idx % C;
    out[idx] = f2bf(in[(size_t)c * R + r]);
}

// dotsT[bh][e][d] = dots[bh][d][e] / NN  (fp32 -> bf16)
__global__ __launch_bounds__(256) void dots_cvt(const float* __restrict__ dots,
                                                us* __restrict__ dotsT) {
    int bh = blockIdx.x, tid = threadIdx.x;
    for (int i = tid; i < 4096; i += 256) {
        int e = i >> 6, d = i & 63;
        dotsT[(size_t)bh * 4096 + i] = f2bf(dots[(size_t)bh * 4096 + d * 64 + e] * (1.f / (float)NN));
    }
}

// ---------------------------------------------------------------
// kv_gemm v3: per block: 128 z-rows x head h. Cols 0-63 = K-head h,
// cols 64-127 = V-head h (kv = z@Wkv). Norm in-register (shuffle),
// rotary per-lane sincos, K/V -> LDS [d][n], fused dots partial
// (K^T V over 128 rows, wave w takes n-slice w*32) -> atomicAdd dots.
// grid (x: b*32+rowtile, y: head 0..7). No Kt/Vt global traffic.
// ---------------------------------------------------------------
__global__ __launch_bounds__(256) void kv_gemm(
    const us* __restrict__ zbf, const float* __restrict__ z_pos,
    const us* __restrict__ WkvT,
    float* __restrict__ dots)
{
    __shared__ __align__(16) char smem[36864];
    us* Abuf = (us*)smem;                 // [128][72] staging
    us* Bbuf = (us*)(smem + 18432);       // [128][72]
    us* Kl = (us*)smem;                   // epilogue: [64 d][136 n] bf16
    us* Vl = (us*)(smem + 17408);         // epilogue: [64 e][136 n]

    const int tid = threadIdx.x;
    const int b  = blockIdx.x >> 5;
    const int r0 = (blockIdx.x & 31) * 128;
    const int h  = blockIdx.y;

    const int wave = tid >> 6, lane = tid & 63;
    const int lr = lane & 15, quad = lane >> 4;
    const int wr = wave & 1, wc = wave >> 1;   // row-half; col-half (0=K,1=V)

    const us* Asrc = zbf + ((size_t)b * NN + r0) * DIMc;

    f32x4 z4 = {0.f, 0.f, 0.f, 0.f};
    f32x4 acc[4][4];
    #pragma unroll
    for (int i = 0; i < 4; ++i)
        #pragma unroll
        for (int j = 0; j < 4; ++j) acc[i][j] = z4;

    for (int kc = 0; kc < 256; kc += 64) {
        for (int i = tid; i < 2048; i += 256) {
            int half = i >> 10, rr = (i & 1023) >> 3, seg = i & 7;
            const us* src;
            if (half) {
                // B rows: 0..63 -> K head h (WkvT row h*64+rr), 64..127 -> V (512 + h*64 + rr-64)
                int wrow = ((rr >> 6) << 9) + h * 64 + (rr & 63);
                src = WkvT + (size_t)wrow * DIMc + kc + seg * 8;
            } else {
                src = Asrc + (size_t)rr * DIMc + kc + seg * 8;
            }
            us* dst = (half ? Bbuf : Abuf) + rr * 72 + seg * 8;
            *(uint4*)dst = *(const uint4*)src;
        }
        __syncthreads();
        #pragma unroll
        for (int ks = 0; ks < 64; ks += 32) {
            s16x8 a[4], bf[4];
            #pragma unroll
            for (int i = 0; i < 4; ++i)
                a[i] = *(const s16x8*)(Abuf + (wr * 64 + i * 16 + lr) * 72 + ks + quad * 8);
            #pragma unroll
            for (int j = 0; j < 4; ++j)
                bf[j] = *(const s16x8*)(Bbuf + (wc * 64 + j * 16 + lr) * 72 + ks + quad * 8);
            #pragma unroll
            for (int i = 0; i < 4; ++i)
                #pragma unroll
                for (int j = 0; j < 4; ++j)
                    acc[i][j] = MFMA16(a[i], bf[j], acc[i][j]);
        }
        __syncthreads();
    }

    // epilogue: norm (+rotary for K) -> LDS [d][n] / [e][n]
    us* myT = wc ? Vl : Kl;
    const float invf = exp2f((float)lr * -0.83048202f);   // 10000^(-lr/16)
    #pragma unroll
    for (int i = 0; i < 4; ++i) {
        float mu_[4], rs_[4];
        #pragma unroll
        for (int r = 0; r < 4; ++r) {
            float s = acc[i][0][r] + acc[i][1][r] + acc[i][2][r] + acc[i][3][r];
            float q2 = acc[i][0][r] * acc[i][0][r] + acc[i][1][r] * acc[i][1][r]
                     + acc[i][2][r] * acc[i][2][r] + acc[i][3][r] * acc[i][3][r];
            s += __shfl_xor(s, 1);  q2 += __shfl_xor(q2, 1);
            s += __shfl_xor(s, 2);  q2 += __shfl_xor(q2, 2);
            s += __shfl_xor(s, 4);  q2 += __shfl_xor(q2, 4);
            s += __shfl_xor(s, 8);  q2 += __shfl_xor(q2, 8);
            float mu = s * (1.f / 64.f);
            float var = q2 * (1.f / 64.f) - mu * mu;
            mu_[r] = mu;
            rs_[r] = rsqrtf(var + 1e-5f);
        }
        float cxr[4], sxr[4], cyr[4], syr[4];
        if (wc == 0) {
            #pragma unroll
            for (int r = 0; r < 4; ++r) {
                const int n = r0 + wr * 64 + i * 16 + quad * 4 + r;
                const float* zp = z_pos + ((size_t)b * NN + n) * 2;
                sincosf(zp[0] * 64.f * invf, &sxr[r], &cxr[r]);
                sincosf(zp[1] * 64.f * invf, &syr[r], &cyr[r]);
            }
        }
        #pragma unroll
        for (int j = 0; j < 4; ++j) {
            union { us s[4]; uint2 u; } pk;
            #pragma unroll
            for (int r = 0; r < 4; ++r) {
                float v0 = (acc[i][j][r] - mu_[r]) * rs_[r];
                if (wc == 0) {
                    float v1 = (acc[i][j ^ 1][r] - mu_[r]) * rs_[r];
                    float cc = (j < 2) ? cxr[r] : cyr[r];
                    float sn = (j < 2) ? sxr[r] : syr[r];
                    v0 = (j & 1) ? fmaf(v0, cc, v1 * sn) : fmaf(v0, cc, -(v1 * sn));
                }
                pk.s[r] = f2bf(v0);
            }
            const int d = j * 16 + lr;
            const int nl = wr * 64 + i * 16 + quad * 4;
            *(uint2*)(myT + d * 136 + nl) = pk.u;
        }
    }
    __syncthreads();

    // fused dots partial: C[d][e] = sum over this block's 128 rows.
    // wave takes k-slice n = wave*32 .. +31 (one 16x16x32 k-step).
    f32x4 acc2[4][4];
    #pragma unroll
    for (int i = 0; i < 4; ++i)
        #pragma unroll
        for (int j = 0; j < 4; ++j) acc2[i][j] = z4;
    {
        s16x8 a2[4], b2[4];
        #pragma unroll
        for (int i = 0; i < 4; ++i)
            a2[i] = *(const s16x8*)(Kl + (i * 16 + lr) * 136 + wave * 32 + quad * 8);
        #pragma unroll
        for (int j = 0; j < 4; ++j)
            b2[j] = *(const s16x8*)(Vl + (j * 16 + lr) * 136 + wave * 32 + quad * 8);
        #pragma unroll
        for (int i = 0; i < 4; ++i)
            #pragma unroll
            for (int j = 0; j < 4; ++j)
                acc2[i][j] = MFMA16(a2[i], b2[j], acc2[i][j]);
    }
    float* dp = dots + ((size_t)b * HH + h) * 4096;
    #pragma unroll
    for (int i = 0; i < 4; ++i)
        #pragma unroll
        for (int j = 0; j < 4; ++j)
            #pragma unroll
            for (int r = 0; r < 4; ++r)
                atomicAdd(dp + (i * 16 + quad * 4 + r) * 64 + j * 16 + lr, acc2[i][j][r]);
}

// ---------------------------------------------------------------
// qt_gemm: q = x@Wq (128x128 tile) -> rotary -> q-LDS -> C2=dotsT x q^T
// -> T[b,n,h*64+e].  grid (x: b*32+rowtile, y: coltile 0..3 = head pair)
// ---------------------------------------------------------------
__global__ __launch_bounds__(256) void qt_gemm(
    const us* __restrict__ xbf, const float* __restrict__ x_pos,
    const us* __restrict__ WqT, const us* __restrict__ dotsT,
    us* __restrict__ T)
{
    __shared__ __align__(16) char smem[71680];
    us* Abuf = (us*)smem;                  // [128][72] staging
    us* Bbuf = (us*)(smem + 18432);
    us* qlds = (us*)smem;                  // epilogue: per-wave [64 rows][76] bf16 (aliases staging)
    float4* tab = (float4*)(smem + 38912); // [128][16] sincos

    const int tid = threadIdx.x;
    const int b  = blockIdx.x >> 5;
    const int r0 = (blockIdx.x & 31) * 128;
    const int ct = blockIdx.y;

    const int wave = tid >> 6, lane = tid & 63;
    const int lr = lane & 15, quad = lane >> 4;
    const int wr = wave & 1, wc = wave >> 1;

    const us* Asrc = xbf + ((size_t)b * NN + r0) * DIMc;
    const us* Bsrc = WqT + (size_t)ct * 128 * DIMc;

    f32x4 z4 = {0.f, 0.f, 0.f, 0.f};
    f32x4 acc[4][4];
    #pragma unroll
    for (int i = 0; i < 4; ++i)
        #pragma unroll
        for (int j = 0; j < 4; ++j) acc[i][j] = z4;

    for (int kc = 0; kc < 256; kc += 64) {
        for (int i = tid; i < 2048; i += 256) {
            int half = i >> 10, rr = (i & 1023) >> 3, seg = i & 7;
            const us* src = (half ? Bsrc : Asrc) + (size_t)rr * DIMc + kc + seg * 8;
            us* dst = (half ? Bbuf : Abuf) + rr * 72 + seg * 8;
            *(uint4*)dst = *(const uint4*)src;
        }
        __syncthreads();
        #pragma unroll
        for (int ks = 0; ks < 64; ks += 32) {
            s16x8 a[4], bf[4];
            #pragma unroll
            for (int i = 0; i < 4; ++i)
                a[i] = *(const s16x8*)(Abuf + (wr * 64 + i * 16 + lr) * 72 + ks + quad * 8);
            #pragma unroll
            for (int j = 0; j < 4; ++j)
                bf[j] = *(const s16x8*)(Bbuf + (wc * 64 + j * 16 + lr) * 72 + ks + quad * 8);
            #pragma unroll
            for (int i = 0; i < 4; ++i)
                #pragma unroll
                for (int j = 0; j < 4; ++j)
                    acc[i][j] = MFMA16(a[i], bf[j], acc[i][j]);
        }
        __syncthreads();
    }

    // sincos table (all tiles)
    for (int idx = tid; idx < 2048; idx += 256) {
        int row = idx >> 4, f = idx & 15;
        float invf = exp2f((float)f * -0.83048202f);
        const float* xp = x_pos + ((size_t)b * NN + r0 + row) * 2;
        float sx, cx, sy, cy;
        sincosf(xp[0] * 64.f * invf, &sx, &cx);
        sincosf(xp[1] * 64.f * invf, &sy, &cy);
        tab[row * 16 + f] = float4{cx, sx, cy, sy};
    }
    __syncthreads();

    // rotary in regs, write q bf16 to per-wave LDS tile [row][d] stride 76
    us* qw = qlds + wave * 64 * 76;
    #pragma unroll
    for (int i = 0; i < 4; ++i) {
        float4 tb[4];
        #pragma unroll
        for (int r = 0; r < 4; ++r)
            tb[r] = tab[(wr * 64 + i * 16 + quad * 4 + r) * 16 + lr];
        #pragma unroll
        for (int j = 0; j < 4; ++j) {
            const int d = j * 16 + lr;
            #pragma unroll
            for (int r = 0; r < 4; ++r) {
                float v0 = acc[i][j][r];
                float v1 = acc[i][j ^ 1][r];
                float cc = (j < 2) ? tb[r].x : tb[r].z;
                float sn = (j < 2) ? tb[r].y : tb[r].w;
                float val = (j & 1) ? fmaf(v0, cc, v1 * sn) : fmaf(v0, cc, -(v1 * sn));
                qw[(i * 16 + quad * 4 + r) * 76 + d] = f2bf(val);
            }
        }
    }
    __syncthreads();

    // second MFMA: A = dotsT[bh] (global, [e][d]), B = q-LDS ([n][d]) -> C2[e][n]
    const int h = ct * 2 + wc;
    const us* dA = dotsT + ((size_t)b * HH + h) * 4096;
    f32x4 acc2[4][4];
    #pragma unroll
    for (int i = 0; i < 4; ++i)
        #pragma unroll
        for (int j = 0; j < 4; ++j) acc2[i][j] = z4;

    #pragma unroll
    for (int ks = 0; ks < 64; ks += 32) {
        s16x8 a2[4], b2[4];
        #pragma unroll
        for (int i = 0; i < 4; ++i)
            a2[i] = *(const s16x8*)(dA + (i * 16 + lr) * 64 + ks + quad * 8);
        #pragma unroll
        for (int j = 0; j < 4; ++j)
            b2[j] = *(const s16x8*)(qw + (j * 16 + lr) * 76 + ks + quad * 8);
        #pragma unroll
        for (int i = 0; i < 4; ++i)
            #pragma unroll
            for (int j = 0; j < 4; ++j)
                acc2[i][j] = MFMA16(a2[i], b2[j], acc2[i][j]);
    }

    // store T[n][h*64+e]: per frag 4 consecutive e (he) -> uint2
    #pragma unroll
    for (int i = 0; i < 4; ++i)
        #pragma unroll
        for (int j = 0; j < 4; ++j) {
            union { us s[4]; uint2 u; } pk;
            #pragma unroll
            for (int r = 0; r < 4; ++r) pk.s[r] = f2bf(acc2[i][j][r]);
            const size_t n = (size_t)b * NN + r0 + wr * 64 + j * 16 + lr;
            const int he = h * 64 + i * 16 + quad * 4;
            *(uint2*)(T + n * INNERc + he) = pk.u;
        }
}

// ---------------------------------------------------------------
// out_gemm v2: C'[o][n] = WoutT[o][:] . T[n][:] + bout[o], direct float4 store
// grid (x: ntile 0..255, y: otile 0..1)
// ---------------------------------------------------------------
__global__ __launch_bounds__(256) void out_gemm(
    const us* __restrict__ T, const us* __restrict__ WoutT,
    const float* __restrict__ bout, float* __restrict__ out)
{
    __shared__ __align__(16) char smem[36864];
    us* Abuf = (us*)smem;              // WoutT rows (o)
    us* Bbuf = (us*)(smem + 18432);    // T rows (n)
    const int tid = threadIdx.x;
    const int n0 = blockIdx.x * 128;
    const int o0 = blockIdx.y * 128;

    const int wave = tid >> 6, lane = tid & 63;
    const int lr = lane & 15, quad = lane >> 4;
    const int ow = wave & 1, wc = wave >> 1;

    const us* Asrc = WoutT + (size_t)o0 * INNERc;
    const us* Bsrc = T + (size_t)n0 * INNERc;

    f32x4 z4 = {0.f, 0.f, 0.f, 0.f};
    f32x4 acc[4][4];
    #pragma unroll
    for (int i = 0; i < 4; ++i)
        #pragma unroll
        for (int j = 0; j < 4; ++j) acc[i][j] = z4;

    for (int kc = 0; kc < 512; kc += 64) {
        for (int i = tid; i < 2048; i += 256) {
            int half = i >> 10, rr = (i & 1023) >> 3, seg = i & 7;
            const us* src = (half ? Bsrc : Asrc) + (size_t)rr * INNERc + kc + seg * 8;
            us* dst = (half ? Bbuf : Abuf) + rr * 72 + seg * 8;
            *(uint4*)dst = *(const uint4*)src;
        }
        __syncthreads();
        #pragma unroll
        for (int ks = 0; ks < 64; ks += 32) {
            s16x8 a[4], bf[4];
            #pragma unroll
            for (int i = 0; i < 4; ++i)
                a[i] = *(const s16x8*)(Abuf + (ow * 64 + i * 16 + lr) * 72 + ks + quad * 8);
            #pragma unroll
            for (int j = 0; j < 4; ++j)
                bf[j] = *(const s16x8*)(Bbuf + (wc * 64 + j * 16 + lr) * 72 + ks + quad * 8);
            #pragma unroll
            for (int i = 0; i < 4; ++i)
                #pragma unroll
                for (int j = 0; j < 4; ++j)
                    acc[i][j] = MFMA16(a[i], bf[j], acc[i][j]);
        }
        __syncthreads();
    }

    // epilogue: out[n][o] = acc + bout[o]; frag rows = o (4 consecutive) -> float4
    #pragma unroll
    for (int i = 0; i < 4; ++i) {
        const int o = o0 + ow * 64 + i * 16 + quad * 4;
        float4 bv = *(const float4*)(bout + o);
        #pragma unroll
        for (int j = 0; j < 4; ++j) {
            const size_t n = (size_t)n0 + wc * 64 + j * 16 + lr;
            float4 v;
            v.x = acc[i][j][0] + bv.x;
            v.y = acc[i][j][1] + bv.y;
            v.z = acc[i][j][2] + bv.z;
            v.w = acc[i][j][3] + bv.w;
            *(float4*)(out + n * DIMc + o) = v;
        }
    }
}

extern "C" void kernel_launch(void* const* d_in, const int* in_sizes, int n_in,
                              void* d_out, int out_size, void* d_ws, size_t ws_size,
                              hipStream_t stream) {
    (void)in_sizes; (void)n_in; (void)out_size; (void)ws_size;
    const float* x     = (const float*)d_in[0];
    const float* z     = (const float*)d_in[1];
    const float* x_pos = (const float*)d_in[2];
    const float* z_pos = (const float*)d_in[3];
    const float* Wq    = (const float*)d_in[4];
    const float* Wkv   = (const float*)d_in[5];
    const float* Wout  = (const float*)d_in[6];
    const float* bout  = (const float*)d_in[7];
    float* out = (float*)d_out;

    char* ws = (char*)d_ws;
    us*    z_bf  = (us*)(ws + 0);                    // 16 MB
    us*    x_bf  = (us*)(ws + 16777216);             // 16 MB
    us*    WqT   = (us*)(ws + 33554432);             // 256 KB
    us*    WkvT  = (us*)(ws + 33816576);             // 512 KB
    us*    WoutT = (us*)(ws + 34340864);             // 256 KB
    float* dots  = (float*)(ws + 34603008);          // 1 MB
    us*    dotsT = (us*)(ws + 35651584);             // 512 KB
    us*    Tb    = (us*)(ws + 36175872);             // 32 MB

    cast_bf16<<<8192, 256, 0, stream>>>(z, z_bf, 2097152);
    cast_bf16<<<8192, 256, 0, stream>>>(x, x_bf, 2097152);
    cast_T<<<512, 256, 0, stream>>>(Wq, WqT, 512, 256);
    cast_T<<<1024, 256, 0, stream>>>(Wkv, WkvT, 1024, 256);
    cast_T<<<512, 256, 0, stream>>>(Wout, WoutT, 256, 512);
    hipMemsetAsync(dots, 0, (size_t)64 * 4096 * 4, stream);

    kv_gemm<<<dim3(256, 8), 256, 0, stream>>>(z_bf, z_pos, WkvT, dots);
    dots_cvt<<<64, 256, 0, stream>>>(dots, dotsT);
    qt_gemm<<<dim3(256, 4), 256, 0, stream>>>(x_bf, x_pos, WqT, dotsT, Tb);
    out_gemm<<<dim3(256, 2), 256, 0, stream>>>(Tb, WoutT, bout, out);
}

// Round 6
// 367.321 us; speedup vs baseline: 1.0621x; 1.0621x over previous
//
#include <hip/hip_runtime.h>
#include <math.h>

#define BB 8
#define NN 4096
#define DIMc 256
#define HH 8
#define DH 64
#define INNERc 512

typedef unsigned short us;
typedef short s16x8 __attribute__((ext_vector_type(8)));   // 8 bf16 operand (4 VGPRs)
typedef float f32x4 __attribute__((ext_vector_type(4)));   // 16x16 C/D frag

static __device__ __forceinline__ us f2bf(float f) {
    union { float f; unsigned int u; } c; c.f = f;
    unsigned int u = c.u;
    return (us)((u + 0x7fffu + ((u >> 16) & 1u)) >> 16);   // RNE
}

#define MFMA16(a, b, c) __builtin_amdgcn_mfma_f32_16x16x32_bf16((a), (b), (c), 0, 0, 0)

// ---------------------------------------------------------------
// cast kernels
// ---------------------------------------------------------------
__global__ __launch_bounds__(256) void cast_bf16(const float* __restrict__ in,
                                                 us* __restrict__ out, int n4) {
    int idx = blockIdx.x * 256 + threadIdx.x;
    if (idx >= n4) return;
    float4 v = ((const float4*)in)[idx];
    union { us s[4]; uint2 u; } pk;
    pk.s[0] = f2bf(v.x); pk.s[1] = f2bf(v.y); pk.s[2] = f2bf(v.z); pk.s[3] = f2bf(v.w);
    ((uint2*)out)[idx] = pk.u;
}

// out[r][c] = in[c][r]; out is R x C, in row-length = R
__global__ __launch_bounds__(256) void cast_T(const float* __restrict__ in,
                                              us* __restrict__ out, int R, int C) {
    int idx = blockIdx.x * 256 + threadIdx.x;
    if (idx >= R * C) return;
    int r = idx / C, c = idx % C;
    out[idx] = f2bf(in[(size_t)c * R + r]);
}

// rope tables: tab[row][f] = (cos_x, sin_x, cos_y, sin_y); rows = b*NN, f 0..15
__global__ __launch_bounds__(256) void rope_tab(const float* __restrict__ pos,
                                                float4* __restrict__ tab) {
    int idx = blockIdx.x * 256 + threadIdx.x;   // 524288 total
    int row = idx >> 4, f = idx & 15;
    float invf = exp2f((float)f * -0.83048202f);   // 10000^(-f/16)
    float sx, cx, sy, cy;
    sincosf(pos[row * 2 + 0] * 64.f * invf, &sx, &cx);
    sincosf(pos[row * 2 + 1] * 64.f * invf, &sy, &cy);
    tab[idx] = float4{cx, sx, cy, sy};
}

// dots_cvt v2: dotsT[bh][e][d] = (sum_c part[c][bh][d][e]) / NN  (fp32 -> bf16)
__global__ __launch_bounds__(256) void dots_cvt(const float* __restrict__ part,
                                                us* __restrict__ dotsT) {
    __shared__ float Cl[64 * 65];
    int bh = blockIdx.x, tid = threadIdx.x;
    for (int i = tid; i < 4096; i += 256) {
        float s = 0.f;
        #pragma unroll
        for (int c = 0; c < 8; ++c) s += part[((size_t)c * 64 + bh) * 4096 + i];
        Cl[(i >> 6) * 65 + (i & 63)] = s;
    }
    __syncthreads();
    for (int o = tid; o < 4096; o += 256) {
        int e = o >> 6, d = o & 63;
        dotsT[(size_t)bh * 4096 + o] = f2bf(Cl[d * 65 + e] * (1.f / (float)NN));
    }
}

// ---------------------------------------------------------------
// kv_gemm v4: block = (b, chunk of 512 z-rows) x head h.
// Per 128-row tile: kv = z@Wkv (cols 0-63 K, 64-127 V), in-register norm,
// rotary (tabz), K/V -> LDS, fused dots partial accumulated in regs over
// 4 tiles. End: cross-wave LDS-atomic reduce, ONE coalesced 16KB partial
// store per block (no global atomics). grid (x: b*8+chunk, y: head).
// ---------------------------------------------------------------
__global__ __launch_bounds__(256) void kv_gemm(
    const us* __restrict__ zbf, const float4* __restrict__ tabz,
    const us* __restrict__ WkvT,
    float* __restrict__ part)
{
    __shared__ __align__(16) char smem[36864];
    us* Abuf = (us*)smem;                 // [128][72] staging
    us* Bbuf = (us*)(smem + 18432);       // [128][72]
    us* Kl = (us*)smem;                   // epilogue: [64 d][136 n] bf16
    us* Vl = (us*)(smem + 17408);         // epilogue: [64 e][136 n]
    float* Rl = (float*)smem;             // reduce: [64][65] fp32 (16.6 KB)

    const int tid = threadIdx.x;
    const int b     = blockIdx.x >> 3;
    const int chunk = blockIdx.x & 7;
    const int h     = blockIdx.y;

    const int wave = tid >> 6, lane = tid & 63;
    const int lr = lane & 15, quad = lane >> 4;
    const int wr = wave & 1, wc = wave >> 1;   // row-half; col-half (0=K,1=V)

    f32x4 z4 = {0.f, 0.f, 0.f, 0.f};
    f32x4 acc2[4][4];
    #pragma unroll
    for (int i = 0; i < 4; ++i)
        #pragma unroll
        for (int j = 0; j < 4; ++j) acc2[i][j] = z4;

    for (int t = 0; t < 4; ++t) {
        const int r0 = chunk * 512 + t * 128;
        const us* Asrc = zbf + ((size_t)b * NN + r0) * DIMc;

        f32x4 acc[4][4];
        #pragma unroll
        for (int i = 0; i < 4; ++i)
            #pragma unroll
            for (int j = 0; j < 4; ++j) acc[i][j] = z4;

        for (int kc = 0; kc < 256; kc += 64) {
            for (int i = tid; i < 2048; i += 256) {
                int half = i >> 10, rr = (i & 1023) >> 3, seg = i & 7;
                const us* src;
                if (half) {
                    // B rows: 0..63 -> K head h, 64..127 -> V head h
                    int wrow = ((rr >> 6) << 9) + h * 64 + (rr & 63);
                    src = WkvT + (size_t)wrow * DIMc + kc + seg * 8;
                } else {
                    src = Asrc + (size_t)rr * DIMc + kc + seg * 8;
                }
                us* dst = (half ? Bbuf : Abuf) + rr * 72 + seg * 8;
                *(uint4*)dst = *(const uint4*)src;
            }
            __syncthreads();
            #pragma unroll
            for (int ks = 0; ks < 64; ks += 32) {
                s16x8 a[4], bf[4];
                #pragma unroll
                for (int i = 0; i < 4; ++i)
                    a[i] = *(const s16x8*)(Abuf + (wr * 64 + i * 16 + lr) * 72 + ks + quad * 8);
                #pragma unroll
                for (int j = 0; j < 4; ++j)
                    bf[j] = *(const s16x8*)(Bbuf + (wc * 64 + j * 16 + lr) * 72 + ks + quad * 8);
                #pragma unroll
                for (int i = 0; i < 4; ++i)
                    #pragma unroll
                    for (int j = 0; j < 4; ++j)
                        acc[i][j] = MFMA16(a[i], bf[j], acc[i][j]);
            }
            __syncthreads();
        }

        // epilogue: norm (+rotary for K via tabz) -> LDS [d][n] / [e][n]
        us* myT = wc ? Vl : Kl;
        #pragma unroll
        for (int i = 0; i < 4; ++i) {
            float mu_[4], rs_[4];
            #pragma unroll
            for (int r = 0; r < 4; ++r) {
                float s = acc[i][0][r] + acc[i][1][r] + acc[i][2][r] + acc[i][3][r];
                float q2 = acc[i][0][r] * acc[i][0][r] + acc[i][1][r] * acc[i][1][r]
                         + acc[i][2][r] * acc[i][2][r] + acc[i][3][r] * acc[i][3][r];
                s += __shfl_xor(s, 1);  q2 += __shfl_xor(q2, 1);
                s += __shfl_xor(s, 2);  q2 += __shfl_xor(q2, 2);
                s += __shfl_xor(s, 4);  q2 += __shfl_xor(q2, 4);
                s += __shfl_xor(s, 8);  q2 += __shfl_xor(q2, 8);
                float mu = s * (1.f / 64.f);
                float var = q2 * (1.f / 64.f) - mu * mu;
                mu_[r] = mu;
                rs_[r] = rsqrtf(var + 1e-5f);
            }
            float4 tb[4];
            if (wc == 0) {
                #pragma unroll
                for (int r = 0; r < 4; ++r) {
                    const int n = r0 + wr * 64 + i * 16 + quad * 4 + r;
                    tb[r] = tabz[((size_t)b * NN + n) * 16 + lr];
                }
            }
            #pragma unroll
            for (int j = 0; j < 4; ++j) {
                union { us s[4]; uint2 u; } pk;
                #pragma unroll
                for (int r = 0; r < 4; ++r) {
                    float v0 = (acc[i][j][r] - mu_[r]) * rs_[r];
                    if (wc == 0) {
                        float v1 = (acc[i][j ^ 1][r] - mu_[r]) * rs_[r];
                        float cc = (j < 2) ? tb[r].x : tb[r].z;
                        float sn = (j < 2) ? tb[r].y : tb[r].w;
                        v0 = (j & 1) ? fmaf(v0, cc, v1 * sn) : fmaf(v0, cc, -(v1 * sn));
                    }
                    pk.s[r] = f2bf(v0);
                }
                const int d = j * 16 + lr;
                const int nl = wr * 64 + i * 16 + quad * 4;
                *(uint2*)(myT + d * 136 + nl) = pk.u;
            }
        }
        __syncthreads();

        // fused dots partial: wave takes n-slice wave*32 (one 16x16x32 k-step)
        {
            s16x8 a2[4], b2[4];
            #pragma unroll
            for (int i = 0; i < 4; ++i)
                a2[i] = *(const s16x8*)(Kl + (i * 16 + lr) * 136 + wave * 32 + quad * 8);
            #pragma unroll
            for (int j = 0; j < 4; ++j)
                b2[j] = *(const s16x8*)(Vl + (j * 16 + lr) * 136 + wave * 32 + quad * 8);
            #pragma unroll
            for (int i = 0; i < 4; ++i)
                #pragma unroll
                for (int j = 0; j < 4; ++j)
                    acc2[i][j] = MFMA16(a2[i], b2[j], acc2[i][j]);
        }
        __syncthreads();   // Kl/Vl consumed; next tile may restage
    }

    // cross-wave reduce in LDS (fp32 ds-atomics), then one coalesced store
    for (int i = tid; i < 4160; i += 256) Rl[i] = 0.f;
    __syncthreads();
    #pragma unroll
    for (int i = 0; i < 4; ++i)
        #pragma unroll
        for (int j = 0; j < 4; ++j)
            #pragma unroll
            for (int r = 0; r < 4; ++r)
                atomicAdd(&Rl[(i * 16 + quad * 4 + r) * 65 + j * 16 + lr], acc2[i][j][r]);
    __syncthreads();
    float* dst = part + ((size_t)chunk * 64 + b * HH + h) * 4096;
    for (int i = tid; i < 4096; i += 256)
        dst[i] = Rl[(i >> 6) * 65 + (i & 63)];
}

// ---------------------------------------------------------------
// qt_gemm: q = x@Wq (128x128 tile) -> rotary (tabx) -> q-LDS ->
// C2 = dotsT x q^T -> T[b,n,h*64+e]. grid (x: b*32+rowtile, y: head pair)
// ---------------------------------------------------------------
__global__ __launch_bounds__(256) void qt_gemm(
    const us* __restrict__ xbf, const float4* __restrict__ tabx,
    const us* __restrict__ WqT, const us* __restrict__ dotsT,
    us* __restrict__ T)
{
    __shared__ __align__(16) char smem[38912];
    us* Abuf = (us*)smem;                  // [128][72] staging
    us* Bbuf = (us*)(smem + 18432);
    us* qlds = (us*)smem;                  // epilogue: per-wave [64 rows][76] bf16

    const int tid = threadIdx.x;
    const int b  = blockIdx.x >> 5;
    const int r0 = (blockIdx.x & 31) * 128;
    const int ct = blockIdx.y;

    const int wave = tid >> 6, lane = tid & 63;
    const int lr = lane & 15, quad = lane >> 4;
    const int wr = wave & 1, wc = wave >> 1;

    const us* Asrc = xbf + ((size_t)b * NN + r0) * DIMc;
    const us* Bsrc = WqT + (size_t)ct * 128 * DIMc;

    f32x4 z4 = {0.f, 0.f, 0.f, 0.f};
    f32x4 acc[4][4];
    #pragma unroll
    for (int i = 0; i < 4; ++i)
        #pragma unroll
        for (int j = 0; j < 4; ++j) acc[i][j] = z4;

    for (int kc = 0; kc < 256; kc += 64) {
        for (int i = tid; i < 2048; i += 256) {
            int half = i >> 10, rr = (i & 1023) >> 3, seg = i & 7;
            const us* src = (half ? Bsrc : Asrc) + (size_t)rr * DIMc + kc + seg * 8;
            us* dst = (half ? Bbuf : Abuf) + rr * 72 + seg * 8;
            *(uint4*)dst = *(const uint4*)src;
        }
        __syncthreads();
        #pragma unroll
        for (int ks = 0; ks < 64; ks += 32) {
            s16x8 a[4], bf[4];
            #pragma unroll
            for (int i = 0; i < 4; ++i)
                a[i] = *(const s16x8*)(Abuf + (wr * 64 + i * 16 + lr) * 72 + ks + quad * 8);
            #pragma unroll
            for (int j = 0; j < 4; ++j)
                bf[j] = *(const s16x8*)(Bbuf + (wc * 64 + j * 16 + lr) * 72 + ks + quad * 8);
            #pragma unroll
            for (int i = 0; i < 4; ++i)
                #pragma unroll
                for (int j = 0; j < 4; ++j)
                    acc[i][j] = MFMA16(a[i], bf[j], acc[i][j]);
        }
        __syncthreads();
    }

    // rotary in regs (tabx direct loads), write q bf16 to per-wave LDS [row][d]
    us* qw = qlds + wave * 64 * 76;
    #pragma unroll
    for (int i = 0; i < 4; ++i) {
        float4 tb[4];
        #pragma unroll
        for (int r = 0; r < 4; ++r) {
            const int n = r0 + wr * 64 + i * 16 + quad * 4 + r;
            tb[r] = tabx[((size_t)b * NN + n) * 16 + lr];
        }
        #pragma unroll
        for (int j = 0; j < 4; ++j) {
            const int d = j * 16 + lr;
            #pragma unroll
            for (int r = 0; r < 4; ++r) {
                float v0 = acc[i][j][r];
                float v1 = acc[i][j ^ 1][r];
                float cc = (j < 2) ? tb[r].x : tb[r].z;
                float sn = (j < 2) ? tb[r].y : tb[r].w;
                float val = (j & 1) ? fmaf(v0, cc, v1 * sn) : fmaf(v0, cc, -(v1 * sn));
                qw[(i * 16 + quad * 4 + r) * 76 + d] = f2bf(val);
            }
        }
    }
    __syncthreads();

    // second MFMA: A = dotsT[bh] ([e][d]), B = q-LDS ([n][d]) -> C2[e][n]
    const int h = ct * 2 + wc;
    const us* dA = dotsT + ((size_t)b * HH + h) * 4096;
    f32x4 acc2[4][4];
    #pragma unroll
    for (int i = 0; i < 4; ++i)
        #pragma unroll
        for (int j = 0; j < 4; ++j) acc2[i][j] = z4;

    #pragma unroll
    for (int ks = 0; ks < 64; ks += 32) {
        s16x8 a2[4], b2[4];
        #pragma unroll
        for (int i = 0; i < 4; ++i)
            a2[i] = *(const s16x8*)(dA + (i * 16 + lr) * 64 + ks + quad * 8);
        #pragma unroll
        for (int j = 0; j < 4; ++j)
            b2[j] = *(const s16x8*)(qw + (j * 16 + lr) * 76 + ks + quad * 8);
        #pragma unroll
        for (int i = 0; i < 4; ++i)
            #pragma unroll
            for (int j = 0; j < 4; ++j)
                acc2[i][j] = MFMA16(a2[i], b2[j], acc2[i][j]);
    }

    // store T[n][h*64+e]: per frag 4 consecutive e (he) -> uint2
    #pragma unroll
    for (int i = 0; i < 4; ++i)
        #pragma unroll
        for (int j = 0; j < 4; ++j) {
            union { us s[4]; uint2 u; } pk;
            #pragma unroll
            for (int r = 0; r < 4; ++r) pk.s[r] = f2bf(acc2[i][j][r]);
            const size_t n = (size_t)b * NN + r0 + wr * 64 + j * 16 + lr;
            const int he = h * 64 + i * 16 + quad * 4;
            *(uint2*)(T + n * INNERc + he) = pk.u;
        }
}

// ---------------------------------------------------------------
// out_gemm: C'[o][n] = WoutT[o][:] . T[n][:] + bout[o], direct float4 store
// grid (x: ntile 0..255, y: otile 0..1)
// ---------------------------------------------------------------
__global__ __launch_bounds__(256) void out_gemm(
    const us* __restrict__ T, const us* __restrict__ WoutT,
    const float* __restrict__ bout, float* __restrict__ out)
{
    __shared__ __align__(16) char smem[36864];
    us* Abuf = (us*)smem;              // WoutT rows (o)
    us* Bbuf = (us*)(smem + 18432);    // T rows (n)
    const int tid = threadIdx.x;
    const int n0 = blockIdx.x * 128;
    const int o0 = blockIdx.y * 128;

    const int wave = tid >> 6, lane = tid & 63;
    const int lr = lane & 15, quad = lane >> 4;
    const int ow = wave & 1, wc = wave >> 1;

    const us* Asrc = WoutT + (size_t)o0 * INNERc;
    const us* Bsrc = T + (size_t)n0 * INNERc;

    f32x4 z4 = {0.f, 0.f, 0.f, 0.f};
    f32x4 acc[4][4];
    #pragma unroll
    for (int i = 0; i < 4; ++i)
        #pragma unroll
        for (int j = 0; j < 4; ++j) acc[i][j] = z4;

    for (int kc = 0; kc < 512; kc += 64) {
        for (int i = tid; i < 2048; i += 256) {
            int half = i >> 10, rr = (i & 1023) >> 3, seg = i & 7;
            const us* src = (half ? Bsrc : Asrc) + (size_t)rr * INNERc + kc + seg * 8;
            us* dst = (half ? Bbuf : Abuf) + rr * 72 + seg * 8;
            *(uint4*)dst = *(const uint4*)src;
        }
        __syncthreads();
        #pragma unroll
        for (int ks = 0; ks < 64; ks += 32) {
            s16x8 a[4], bf[4];
            #pragma unroll
            for (int i = 0; i < 4; ++i)
                a[i] = *(const s16x8*)(Abuf + (ow * 64 + i * 16 + lr) * 72 + ks + quad * 8);
            #pragma unroll
            for (int j = 0; j < 4; ++j)
                bf[j] = *(const s16x8*)(Bbuf + (wc * 64 + j * 16 + lr) * 72 + ks + quad * 8);
            #pragma unroll
            for (int i = 0; i < 4; ++i)
                #pragma unroll
                for (int j = 0; j < 4; ++j)
                    acc[i][j] = MFMA16(a[i], bf[j], acc[i][j]);
        }
        __syncthreads();
    }

    #pragma unroll
    for (int i = 0; i < 4; ++i) {
        const int o = o0 + ow * 64 + i * 16 + quad * 4;
        float4 bv = *(const float4*)(bout + o);
        #pragma unroll
        for (int j = 0; j < 4; ++j) {
            const size_t n = (size_t)n0 + wc * 64 + j * 16 + lr;
            float4 v;
            v.x = acc[i][j][0] + bv.x;
            v.y = acc[i][j][1] + bv.y;
            v.z = acc[i][j][2] + bv.z;
            v.w = acc[i][j][3] + bv.w;
            *(float4*)(out + n * DIMc + o) = v;
        }
    }
}

extern "C" void kernel_launch(void* const* d_in, const int* in_sizes, int n_in,
                              void* d_out, int out_size, void* d_ws, size_t ws_size,
                              hipStream_t stream) {
    (void)in_sizes; (void)n_in; (void)out_size; (void)ws_size;
    const float* x     = (const float*)d_in[0];
    const float* z     = (const float*)d_in[1];
    const float* x_pos = (const float*)d_in[2];
    const float* z_pos = (const float*)d_in[3];
    const float* Wq    = (const float*)d_in[4];
    const float* Wkv   = (const float*)d_in[5];
    const float* Wout  = (const float*)d_in[6];
    const float* bout  = (const float*)d_in[7];
    float* out = (float*)d_out;

    char* ws = (char*)d_ws;
    us*     z_bf  = (us*)(ws + 0);                   // 16 MB
    us*     x_bf  = (us*)(ws + 16777216);            // 16 MB
    us*     WqT   = (us*)(ws + 33554432);            // 256 KB
    us*     WkvT  = (us*)(ws + 33816576);            // 512 KB
    us*     WoutT = (us*)(ws + 34340864);            // 256 KB
    us*     dotsT = (us*)(ws + 34603008);            // 512 KB
    float*  part  = (float*)(ws + 35127296);         // 8 MB  [8][64][4096]
    float4* tabx  = (float4*)(ws + 43515904);        // 8 MB
    float4* tabz  = (float4*)(ws + 51904512);        // 8 MB
    us*     Tb    = (us*)(ws + 60293120);            // 32 MB

    cast_bf16<<<8192, 256, 0, stream>>>(z, z_bf, 2097152);
    cast_bf16<<<8192, 256, 0, stream>>>(x, x_bf, 2097152);
    cast_T<<<512, 256, 0, stream>>>(Wq, WqT, 512, 256);
    cast_T<<<1024, 256, 0, stream>>>(Wkv, WkvT, 1024, 256);
    cast_T<<<512, 256, 0, stream>>>(Wout, WoutT, 256, 512);
    rope_tab<<<2048, 256, 0, stream>>>(z_pos, tabz);
    rope_tab<<<2048, 256, 0, stream>>>(x_pos, tabx);

    kv_gemm<<<dim3(64, 8), 256, 0, stream>>>(z_bf, tabz, WkvT, part);
    dots_cvt<<<64, 256, 0, stream>>>(part, dotsT);
    qt_gemm<<<dim3(256, 4), 256, 0, stream>>>(x_bf, tabx, WqT, dotsT, Tb);
    out_gemm<<<dim3(256, 2), 256, 0, stream>>>(Tb, WoutT, bout, out);
}